// Round 1
// baseline (449.374 us; speedup 1.0000x reference)
//
#include <hip/hip_runtime.h>
#include <hip/hip_bf16.h>
#include <hip/hip_cooperative_groups.h>
#include <cstdint>
#include <cstddef>

namespace cg = cooperative_groups;

#define HW    32768     // 128*256 feature pixels per image
#define NCLS  19
#define VIEWS 50
#define NT    38        // 2 images * 19 classes
#define NR    1900      // NT * VIEWS anchor rows
#define NRP   1920      // padded to 30*64 tiles
#define CH    256       // channels
#define CAPB  256       // per-(class,chunk) segment cap (hard bound: 256 pixels/chunk/image)
#define CAPD  3072      // dense per-class list cap (mean ~1724, sd ~41)
#define GDIM  512       // cooperative grid: 2 blocks/CU * 256 CUs
#define NTILE 1830      // 900 full (cm) + 465 + 465 upper-tri (vis, aux)
#define BLDS  272       // LDS row stride (ushorts): even 4-bank-span distribution

// ---- workspace layout (FLOAT units) ----
#define OFF_LD    0u         // int   [2][HW]                    = 65536
#define OFF_SEL   65536u     // int   [1900] (pad 2048)
#define OFF_CNTPB 67584u     // int   [NT*128]=4864 (pad 5120)
#define OFF_KEYS  72704u     // ull   [NT][128][CAPB] = 2490368 floats (8B aligned)
#define OFF_FCF   2563072u   // ushort[NRP][CH] = 245760 floats
#define OFF_FOF   2808832u   // ushort[NRP][CH] = 245760 floats
#define OFF_NEG   3054592u   // float [3][NR] = 5700 (pad 5760)
#define OFF_POS   3060352u   // float [3][NR][100] = 570000
// end 3630352 floats = 14.5 MB (workspace is 256 MiB)

typedef __attribute__((ext_vector_type(8))) short short8;
typedef __attribute__((ext_vector_type(4))) float f32x4;

__device__ __forceinline__ unsigned rotl32(unsigned x, int d) {
    return (x << d) | (x >> (32 - d));
}

// One cooperative kernel, 5 phases, 4 grid syncs.
// A: threefry + label downsample + segmented per-(class,chunk) key push (race-free, no memset)
// B: exact top-50 per (image,class) via chunk prefix-sum + LDS compaction + 256-bin histogram
// C: gather + l2-normalize -> bf16
// D: bf16 MFMA Gram (A.B^T * 10) with fused InfoNCE epilogue (z=0 full, z=1/2 upper-tri+mirror)
// E: per-anchor InfoNCE reduction
__global__ __launch_bounds__(256, 2) void fused_kernel(
    const int* __restrict__ label, const float* __restrict__ cf, const float* __restrict__ of,
    int* __restrict__ ld, int* __restrict__ sel, int* __restrict__ cntpb,
    unsigned long long* __restrict__ keys, unsigned short* __restrict__ fcf,
    unsigned short* __restrict__ fof, float* __restrict__ negsum,
    float* __restrict__ posdot, float* __restrict__ out)
{
    cg::grid_group grid = cg::this_grid();
    int tid = threadIdx.x;
    int b = blockIdx.x;

    // phase-multiplexed big buffer: D uses 64*272*2 = 34816 B; B uses 27136 B
    __shared__ __align__(16) char smem[34816];
    __shared__ int lcnt[NT];
    __shared__ unsigned hist[256];
    __shared__ int s_B, s_nbelow, s_ncand;
    __shared__ float pc4[4], po4[4];
    __shared__ float negs[64], negsB[64];
    __shared__ float part3[3];

    // ---------------- Phase A: RNG + downsample + segmented push ----------------
    if (b < 128) {
        int j = b * 256 + tid;                 // 0..32767
        unsigned x0 = (unsigned)j, x1 = (unsigned)(j + HW);
        const unsigned ks0 = 0u, ks1 = 42u, ks2 = 0x1BD11BDAu ^ 0u ^ 42u;
        x0 += ks0; x1 += ks1;
#define TF_RND(r) { x0 += x1; x1 = rotl32(x1, r); x1 ^= x0; }
        TF_RND(13) TF_RND(15) TF_RND(26) TF_RND(6)   x0 += ks1; x1 += ks2 + 1u;
        TF_RND(17) TF_RND(29) TF_RND(16) TF_RND(24)  x0 += ks2; x1 += ks0 + 2u;
        TF_RND(13) TF_RND(15) TF_RND(26) TF_RND(6)   x0 += ks0; x1 += ks1 + 3u;
        TF_RND(17) TF_RND(29) TF_RND(16) TF_RND(24)  x0 += ks1; x1 += ks2 + 4u;
        TF_RND(13) TF_RND(15) TF_RND(26) TF_RND(6)   x0 += ks2; x1 += ks0 + 5u;
#undef TF_RND
        float r0 = __uint_as_float((x0 >> 9) | 0x3f800000u) - 1.0f;
        float r1 = __uint_as_float((x1 >> 9) | 0x3f800000u) - 1.0f;
        int y = j >> 8, x = j & 255;
        int off = (y << 2) * 1024 + (x << 2);
        int c0 = label[off];
        int c1 = label[512 * 1024 + off];
        ld[j]      = c0;
        ld[HW + j] = c1;
        if (j < 3 * NR) negsum[j] = 0.0f;
        if (j < 3) out[j] = 0.0f;

        if (tid < NT) lcnt[tid] = 0;
        __syncthreads();
        int t0 = c0, t1 = NCLS + c1;           // disjoint ranges: [0,19) vs [19,38)
        int p0 = atomicAdd(&lcnt[t0], 1);      // <= 255: hard bound, no clamp needed
        int p1 = atomicAdd(&lcnt[t1], 1);
        keys[((size_t)t0 * 128 + b) * CAPB + p0] =
            (((unsigned long long)__float_as_uint(r0)) << 32) | (unsigned)j;
        keys[((size_t)t1 * 128 + b) * CAPB + p1] =
            (((unsigned long long)__float_as_uint(r1)) << 32) | (unsigned)j;
        __syncthreads();
        if (tid < NT) cntpb[tid * 128 + b] = lcnt[tid];
    }
    grid.sync();

    // ---------------- Phase B: exact top-50 select ----------------
    if (b < NT) {
        int t = b;
        unsigned long long* dense = (unsigned long long*)smem;            // 24576 B
        unsigned long long* cand  = (unsigned long long*)(smem + 24576);  // 2048 B
        int* csc = (int*)(smem + 26624);                                  // 512 B

        int mycnt = 0;
        if (tid < 128) { mycnt = cntpb[t * 128 + tid]; csc[tid] = mycnt; }
        hist[tid] = 0;
        if (tid == 0) { s_B = 256; s_nbelow = 0; s_ncand = 0; }
        __syncthreads();
        // inclusive scan of 128 chunk counts
        for (int s = 1; s < 128; s <<= 1) {
            int add = (tid < 128 && tid >= s) ? csc[tid - s] : 0;
            __syncthreads();
            if (tid < 128) csc[tid] += add;
            __syncthreads();
        }
        int total = csc[127];
        // compact segmented keys into dense LDS list
        if (tid < 128) {
            int excl = csc[tid] - mycnt;
            const unsigned long long* src = keys + ((size_t)t * 128 + tid) * CAPB;
            for (int q = 0; q < mycnt; ++q) {
                int dst = excl + q;
                if (dst < CAPD) dense[dst] = src[q];
            }
        }
        __syncthreads();
        int cnt = min(total, CAPD);

        unsigned long long kreg[12];
        int binreg[12];
        int nk = 0;
        for (int p = tid; p < cnt; p += 256) {
            unsigned long long k = dense[p];
            unsigned v = (unsigned)(__uint_as_float((unsigned)(k >> 32)) * 8388608.0f);
            int bn = (int)(v >> 15);
            kreg[nk] = k; binreg[nk] = bn; nk++;
            atomicAdd(&hist[bn], 1u);
        }
        __syncthreads();

        if (cnt >= VIEWS) {
            for (int s = 1; s < 256; s <<= 1) {
                unsigned add = (tid >= s) ? hist[tid - s] : 0u;
                unsigned cur = hist[tid];
                __syncthreads();
                hist[tid] = cur + add;
                __syncthreads();
            }
            unsigned cum  = hist[tid];
            unsigned prev = (tid > 0) ? hist[tid - 1] : 0u;
            if (cum >= VIEWS && prev < VIEWS) s_B = tid;
            __syncthreads();
            int B = s_B;
            for (int q = 0; q < nk; ++q) {
                if (binreg[q] < B) {
                    int pos = atomicAdd(&s_nbelow, 1);
                    if (pos < VIEWS) sel[t * VIEWS + pos] = (int)(kreg[q] & 0xffffffffu);
                } else if (binreg[q] == B) {
                    int pos = atomicAdd(&s_ncand, 1);
                    if (pos < 256) cand[pos] = kreg[q];
                }
            }
            __syncthreads();
            int nbelow = s_nbelow;
            int need   = VIEWS - nbelow;
            int ncand  = min(s_ncand, 256);
            if (tid < 64) {
                unsigned long long r0 = (tid       < ncand) ? cand[tid]       : ~0ull;
                unsigned long long r1 = (tid + 64  < ncand) ? cand[tid + 64]  : ~0ull;
                unsigned long long r2 = (tid + 128 < ncand) ? cand[tid + 128] : ~0ull;
                unsigned long long r3 = (tid + 192 < ncand) ? cand[tid + 192] : ~0ull;
                for (int v = 0; v < need; ++v) {
                    unsigned long long a = (r0 < r1) ? r0 : r1;
                    unsigned long long bb = (r2 < r3) ? r2 : r3;
                    unsigned long long best = (a < bb) ? a : bb;
                    for (int m = 32; m >= 1; m >>= 1) {
                        unsigned long long o = __shfl_xor(best, m);
                        if (o < best) best = o;
                    }
                    if (tid == 0) sel[t * VIEWS + nbelow + v] = (int)(best & 0xffffffffu);
                    if (r0 == best) r0 = ~0ull;
                    if (r1 == best) r1 = ~0ull;
                    if (r2 == best) r2 = ~0ull;
                    if (r3 == best) r3 = ~0ull;
                }
            }
        } else {
            for (int q = 0; q < nk; ++q) {
                int pos = atomicAdd(&s_nbelow, 1);
                if (pos < VIEWS) sel[t * VIEWS + pos] = (int)(kreg[q] & 0xffffffffu);
            }
            __syncthreads();
            if (tid == 0) {
                int fill = s_nbelow;
                int n = t / NCLS, c = t % NCLS;
                const int* ldn = ld + n * HW;
                for (int j = 0; j < HW && fill < VIEWS; ++j)
                    if (ldn[j] != c) sel[t * VIEWS + fill++] = j;
            }
        }
    }
    grid.sync();

    // ---------------- Phase C: gather + normalize -> bf16 ----------------
    for (int r = b; r < NRP; r += GDIM) {
        int ch = tid;
        if (r >= NR) {
            fcf[r * CH + ch] = 0;
            fof[r * CH + ch] = 0;
        } else {
            int t = r / VIEWS;
            int n = t / NCLS;
            int idx = sel[r];
            float vc = cf[(size_t)(n * CH + ch) * HW + idx];
            float vo = of[(size_t)(n * CH + ch) * HW + idx];
            float sc = vc * vc, so = vo * vo;
            for (int m = 32; m >= 1; m >>= 1) {
                sc += __shfl_xor(sc, m);
                so += __shfl_xor(so, m);
            }
            int wave = ch >> 6, lane = ch & 63;
            if (lane == 0) { pc4[wave] = sc; po4[wave] = so; }
            __syncthreads();
            float nc = fmaxf(sqrtf(pc4[0] + pc4[1] + pc4[2] + pc4[3]), 1e-12f);
            float no = fmaxf(sqrtf(po4[0] + po4[1] + po4[2] + po4[3]), 1e-12f);
            __hip_bfloat16 hc = __float2bfloat16(vc / nc);
            __hip_bfloat16 ho = __float2bfloat16(vo / no);
            fcf[r * CH + ch] = *(unsigned short*)&hc;
            fof[r * CH + ch] = *(unsigned short*)&ho;
            __syncthreads();   // pc4/po4 reuse guard for next grid-stride iteration
        }
    }
    grid.sync();

    // ---------------- Phase D: MFMA Gram + fused InfoNCE epilogue ----------------
    for (int T = b; T < NTILE; T += GDIM) {
        int z, by, bx;
        if (T < 900) { z = 0; by = T / 30; bx = T % 30; }
        else {
            int u = T - 900;
            z = 1 + u / 465;
            int v = u % 465;
            int rr_ = 0, acc_ = 0;
            while (acc_ + (30 - rr_) <= v) { acc_ += 30 - rr_; ++rr_; }
            by = rr_; bx = rr_ + (v - acc_);            // upper triangle, bx >= by
        }
        bool mirror = (z >= 1) && (by < bx);
        const unsigned short* A  = (z == 2) ? fof : fcf;
        const unsigned short* Bp = (z == 1) ? fcf : fof;
        int i0 = by * 64, j0 = bx * 64;
        int wave = tid >> 6, lane = tid & 63;
        unsigned short (*Bs)[BLDS] = (unsigned short (*)[BLDS])(void*)smem;
        if (tid < 64) { negs[tid] = 0.0f; negsB[tid] = 0.0f; }

        // B tile -> registers (coalesced dwordx4)
        short8 breg[8];
#pragma unroll
        for (int m = 0; m < 8; ++m) {
            int e = m * 256 + tid;
            int row = e >> 5, chc = (e & 31) * 8;
            breg[m] = *(const short8*)(Bp + (size_t)(j0 + row) * CH + chc);
        }
        // A fragments direct to VGPR
        const unsigned short* pa = A + (size_t)(i0 + wave * 16 + (lane & 15)) * CH + (lane >> 4) * 8;
        short8 af[8];
#pragma unroll
        for (int k = 0; k < 8; ++k) af[k] = *(const short8*)(pa + k * 32);
        // registers -> LDS
#pragma unroll
        for (int m = 0; m < 8; ++m) {
            int e = m * 256 + tid;
            int row = e >> 5, chc = (e & 31) * 8;
            *(short8*)&Bs[row][chc] = breg[m];
        }
        __syncthreads();

        f32x4 acc[4] = {{0,0,0,0},{0,0,0,0},{0,0,0,0},{0,0,0,0}};
#pragma unroll
        for (int k = 0; k < 8; ++k) {
#pragma unroll
            for (int bb = 0; bb < 4; ++bb) {
                short8 bf = *(const short8*)&Bs[bb * 16 + (lane & 15)][k * 32 + (lane >> 4) * 8];
                acc[bb] = __builtin_amdgcn_mfma_f32_16x16x32_bf16(af[k], bf, acc[bb], 0, 0, 0);
            }
        }

        // epilogue: C/D layout col=lane&15, row=(lane>>4)*4+reg (+wave*16)
        float* pd = posdot + (size_t)z * NR * 100;
        int col = lane & 15, quad = lane >> 4;
        float negB4[4] = {0.0f, 0.0f, 0.0f, 0.0f};
#pragma unroll
        for (int rr = 0; rr < 4; ++rr) {
            int irow = wave * 16 + quad * 4 + rr;
            int i = i0 + irow;
            bool iok = (i < NR);
            int ci = (i / VIEWS) % NCLS;
            float negacc = 0.0f;
#pragma unroll
            for (int bb = 0; bb < 4; ++bb) {
                int jj = j0 + bb * 16 + col;
                if (!iok || jj >= NR) continue;
                int cj = (jj / VIEWS) % NCLS;
                float d = acc[bb][rr] * 10.0f;   // 1/temp
                if (ci == cj) {
                    int p = (jj / (NCLS * VIEWS)) * VIEWS + (jj % VIEWS);
                    pd[(size_t)i * 100 + p] = d;
                    if (mirror) {
                        int q = (i / (NCLS * VIEWS)) * VIEWS + (i % VIEWS);
                        pd[(size_t)jj * 100 + q] = d;
                    }
                } else {
                    float e = __expf(d);
                    negacc += e;
                    if (mirror) negB4[bb] += e;
                }
            }
            for (int m = 8; m >= 1; m >>= 1) negacc += __shfl_xor(negacc, m);
            if (col == 0 && iok) negs[irow] = negacc;
        }
        if (mirror) {
#pragma unroll
            for (int bb = 0; bb < 4; ++bb) {
                float v = negB4[bb];
                v += __shfl_xor(v, 16);
                v += __shfl_xor(v, 32);
                if (quad == 0) atomicAdd(&negsB[bb * 16 + col], v);
            }
        }
        __syncthreads();
        if (tid < 64) {
            int i = i0 + tid;
            if (i < NR) atomicAdd(&negsum[z * NR + i], negs[tid]);
            if (mirror) {
                int jj = j0 + tid;
                if (jj < NR) atomicAdd(&negsum[z * NR + jj], negsB[tid]);
            }
        }
    }
    grid.sync();

    // ---------------- Phase E: per-anchor InfoNCE ----------------
    if (b < 23) {
        int g = b * 256 + tid;
        if (tid < 3) part3[tid] = 0.0f;
        __syncthreads();
        if (g < 3 * NR) {
            int l = g / NR, i = g % NR;
            float NL = negsum[l * NR + i];
            int pself = (i / (NCLS * VIEWS)) * VIEWS + (i % VIEWS);
            const float* pdp = posdot + ((size_t)l * NR + i) * 100;
            float s = 0.0f;
            for (int p = 0; p < 100; ++p) {
                if (p == pself) continue;
                float d = pdp[p];
                s += d - logf(__expf(d) + NL);
            }
            atomicAdd(&part3[l], s);
        }
        __syncthreads();
        if (tid < 3)
            atomicAdd(&out[tid], -part3[tid] * (1.0f / (99.0f * 1900.0f)));
    }
}

extern "C" void kernel_launch(void* const* d_in, const int* in_sizes, int n_in,
                              void* d_out, int out_size, void* d_ws, size_t ws_size,
                              hipStream_t stream) {
    (void)in_sizes; (void)n_in; (void)out_size; (void)ws_size;
    const int*   label = (const int*)d_in[0];
    const float* cf    = (const float*)d_in[1];
    const float* of    = (const float*)d_in[2];
    float* ws = (float*)d_ws;
    int*                ld     = (int*)(ws + OFF_LD);
    int*                sel    = (int*)(ws + OFF_SEL);
    int*                cntpb  = (int*)(ws + OFF_CNTPB);
    unsigned long long* keys   = (unsigned long long*)(ws + OFF_KEYS);
    unsigned short*     fcf    = (unsigned short*)(ws + OFF_FCF);
    unsigned short*     fof    = (unsigned short*)(ws + OFF_FOF);
    float*              negsum = ws + OFF_NEG;
    float*              posdot = ws + OFF_POS;
    float*              out    = (float*)d_out;

    void* args[] = {(void*)&label, (void*)&cf, (void*)&of, (void*)&ld, (void*)&sel,
                    (void*)&cntpb, (void*)&keys, (void*)&fcf, (void*)&fof,
                    (void*)&negsum, (void*)&posdot, (void*)&out};
    hipLaunchCooperativeKernel((const void*)fused_kernel, dim3(GDIM), dim3(256),
                               args, 0, stream);
}

// Round 2
// 277.778 us; speedup vs baseline: 1.6177x; 1.6177x over previous
//
#include <hip/hip_runtime.h>
#include <hip/hip_bf16.h>
#include <cstdint>
#include <cstddef>

#define HW    32768     // 128*256 feature pixels per image
#define NCLS  19
#define VIEWS 50
#define NT    38        // 2 images * 19 classes
#define NR    1900      // NT * VIEWS anchor rows
#define NRP   1920      // padded to 30*64 tiles
#define CH    256       // channels
#define CAPS  2560      // LDS candidate cap per (image,class): mean ~1724, sd ~41 (20 sigma)

// ---- workspace layout (FLOAT units) ----
#define OFF_SEL 0u         // int   [1900] (pad 2048)
#define OFF_NEG 2048u      // float [3][NR] = 5700 (pad 5760)
#define OFF_POS 7808u      // float [3][NR][100] = 570000 (pad to 577856)
#define OFF_FCF 577856u    // ushort[NRP][CH] = 245760 floats
#define OFF_FOF 823616u    // ushort[NRP][CH] = 245760 floats
// end 1069376 floats = 4.3 MB

typedef __attribute__((ext_vector_type(8))) short short8;
typedef __attribute__((ext_vector_type(4))) float f32x4;

__device__ __forceinline__ unsigned rotl32(unsigned x, int d) {
    return (x << d) | (x >> (32 - d));
}

// Kernel 1: fused sampling. One block per (image,class): scan downsampled labels,
// threefry2x32 (key 42) ONLY on matching pixels (~1724 instead of 32768*38),
// push (randbits<<32 | pixel) into LDS, then exact order-free top-50 via the
// verified 256-bin histogram select. Also zeroes negsum/out (replaces memset).
__global__ __launch_bounds__(256) void sample_kernel(const int* __restrict__ label,
                                                     int* __restrict__ sel,
                                                     float* __restrict__ negsum,
                                                     float* __restrict__ out) {
    int t = blockIdx.x, tid = threadIdx.x;
    int n = t / NCLS, c = t % NCLS;
    __shared__ unsigned long long dense[CAPS];     // 20 KB
    __shared__ unsigned long long cand[256];       // 2 KB
    __shared__ unsigned hist[256];
    __shared__ int s_cnt, s_B, s_nbelow, s_ncand;
    hist[tid] = 0;
    if (tid == 0) { s_cnt = 0; s_B = 256; s_nbelow = 0; s_ncand = 0; }
    if (tid < 150) negsum[t * 150 + tid] = 0.0f;   // 38*150 = 5700 = 3*NR
    if (t == 0 && tid < 3) out[tid] = 0.0f;
    __syncthreads();

    const int* lab = label + (size_t)n * 512 * 1024;
    for (int j = tid; j < HW; j += 256) {
        int lv = lab[((j >> 8) << 2) * 1024 + ((j & 255) << 2)];   // nearest-neighbour downsample
        if (lv != c) continue;
        unsigned x0 = (unsigned)j, x1 = (unsigned)(j + HW);
        const unsigned ks0 = 0u, ks1 = 42u, ks2 = 0x1BD11BDAu ^ 0u ^ 42u;
        x0 += ks0; x1 += ks1;
#define TF_RND(r) { x0 += x1; x1 = rotl32(x1, r); x1 ^= x0; }
        TF_RND(13) TF_RND(15) TF_RND(26) TF_RND(6)   x0 += ks1; x1 += ks2 + 1u;
        TF_RND(17) TF_RND(29) TF_RND(16) TF_RND(24)  x0 += ks2; x1 += ks0 + 2u;
        TF_RND(13) TF_RND(15) TF_RND(26) TF_RND(6)   x0 += ks0; x1 += ks1 + 3u;
        TF_RND(17) TF_RND(29) TF_RND(16) TF_RND(24)  x0 += ks1; x1 += ks2 + 4u;
        TF_RND(13) TF_RND(15) TF_RND(26) TF_RND(6)   x0 += ks2; x1 += ks0 + 5u;
#undef TF_RND
        unsigned xb = n ? x1 : x0;
        float r = __uint_as_float((xb >> 9) | 0x3f800000u) - 1.0f;
        int pos = atomicAdd(&s_cnt, 1);
        if (pos < CAPS)
            dense[pos] = (((unsigned long long)__float_as_uint(r)) << 32) | (unsigned)j;
    }
    __syncthreads();
    int cnt = min(s_cnt, CAPS);

    unsigned long long kreg[12];
    int binreg[12];
    int nk = 0;
    for (int p = tid; p < cnt; p += 256) {
        unsigned long long k = dense[p];
        unsigned v = (unsigned)(__uint_as_float((unsigned)(k >> 32)) * 8388608.0f);
        int bn = (int)(v >> 15);
        kreg[nk] = k; binreg[nk] = bn; nk++;
        atomicAdd(&hist[bn], 1u);
    }
    __syncthreads();

    if (cnt >= VIEWS) {
        for (int s = 1; s < 256; s <<= 1) {
            unsigned add = (tid >= s) ? hist[tid - s] : 0u;
            unsigned cur = hist[tid];
            __syncthreads();
            hist[tid] = cur + add;
            __syncthreads();
        }
        unsigned cum  = hist[tid];
        unsigned prev = (tid > 0) ? hist[tid - 1] : 0u;
        if (cum >= VIEWS && prev < VIEWS) s_B = tid;
        __syncthreads();
        int B = s_B;
        for (int q = 0; q < nk; ++q) {
            if (binreg[q] < B) {
                int pos = atomicAdd(&s_nbelow, 1);
                if (pos < VIEWS) sel[t * VIEWS + pos] = (int)(kreg[q] & 0xffffffffu);
            } else if (binreg[q] == B) {
                int pos = atomicAdd(&s_ncand, 1);
                if (pos < 256) cand[pos] = kreg[q];
            }
        }
        __syncthreads();
        int nbelow = s_nbelow;
        int need   = VIEWS - nbelow;
        int ncand  = min(s_ncand, 256);
        if (tid < 64) {
            unsigned long long r0 = (tid       < ncand) ? cand[tid]       : ~0ull;
            unsigned long long r1 = (tid + 64  < ncand) ? cand[tid + 64]  : ~0ull;
            unsigned long long r2 = (tid + 128 < ncand) ? cand[tid + 128] : ~0ull;
            unsigned long long r3 = (tid + 192 < ncand) ? cand[tid + 192] : ~0ull;
            for (int v = 0; v < need; ++v) {
                unsigned long long a = (r0 < r1) ? r0 : r1;
                unsigned long long b = (r2 < r3) ? r2 : r3;
                unsigned long long best = (a < b) ? a : b;
                for (int m = 32; m >= 1; m >>= 1) {
                    unsigned long long o = __shfl_xor(best, m);
                    if (o < best) best = o;
                }
                if (tid == 0) sel[t * VIEWS + nbelow + v] = (int)(best & 0xffffffffu);
                if (r0 == best) r0 = ~0ull;
                if (r1 == best) r1 = ~0ull;
                if (r2 == best) r2 = ~0ull;
                if (r3 == best) r3 = ~0ull;
            }
        }
    } else {
        for (int q = 0; q < nk; ++q) {
            int pos = atomicAdd(&s_nbelow, 1);
            if (pos < VIEWS) sel[t * VIEWS + pos] = (int)(kreg[q] & 0xffffffffu);
        }
        __syncthreads();
        if (tid == 0) {
            int fill = s_nbelow;
            for (int j = 0; j < HW && fill < VIEWS; ++j) {
                int lv = lab[((j >> 8) << 2) * 1024 + ((j & 255) << 2)];
                if (lv != c) sel[t * VIEWS + fill++] = j;
            }
        }
    }
}

// Kernel 2: gather sampled pixels, l2-normalize, store bf16 bits; pad rows zeroed.
__global__ __launch_bounds__(256) void gather_kernel(const float* __restrict__ cf,
                                                     const float* __restrict__ of,
                                                     const int* __restrict__ sel,
                                                     unsigned short* __restrict__ fcf,
                                                     unsigned short* __restrict__ fof) {
    int r = blockIdx.x;              // 0..NRP-1
    int ch = threadIdx.x;
    if (r >= NR) {
        fcf[r * CH + ch] = 0;
        fof[r * CH + ch] = 0;
        return;
    }
    int t = r / VIEWS;
    int n = t / NCLS;
    int idx = sel[r];
    float vc = cf[(size_t)(n * CH + ch) * HW + idx];
    float vo = of[(size_t)(n * CH + ch) * HW + idx];
    __shared__ float partc[4], parto[4];
    float sc = vc * vc, so = vo * vo;
    for (int m = 32; m >= 1; m >>= 1) {
        sc += __shfl_xor(sc, m);
        so += __shfl_xor(so, m);
    }
    int wave = ch >> 6, lane = ch & 63;
    if (lane == 0) { partc[wave] = sc; parto[wave] = so; }
    __syncthreads();
    float nc = fmaxf(sqrtf(partc[0] + partc[1] + partc[2] + partc[3]), 1e-12f);
    float no = fmaxf(sqrtf(parto[0] + parto[1] + parto[2] + parto[3]), 1e-12f);
    __hip_bfloat16 hc = __float2bfloat16(vc / nc);
    __hip_bfloat16 ho = __float2bfloat16(vo / no);
    fcf[r * CH + ch] = *(unsigned short*)&hc;
    fof[r * CH + ch] = *(unsigned short*)&ho;
}

// Kernel 3: bf16 MFMA Gram (A.B^T * 10) with fused InfoNCE epilogue.
// z=0: cm (fcf,fof) full; z=1 vis / z=2 aux symmetric: tiles i0<=j0 only,
// strict-upper mirrors the epilogue.
#define BLDS 272
__global__ __launch_bounds__(256) void gram_kernel(const unsigned short* __restrict__ fcf,
                                                   const unsigned short* __restrict__ fof,
                                                   float* __restrict__ negsum,
                                                   float* __restrict__ posdot) {
    int z = blockIdx.z;
    bool sym = (z >= 1);
    if (sym && blockIdx.y > blockIdx.x) return;     // lower-triangle tiles skipped
    bool mirror = sym && (blockIdx.y < blockIdx.x);
    const unsigned short* A = (z == 2) ? fof : fcf;
    const unsigned short* B = (z == 1) ? fcf : fof;
    int i0 = blockIdx.y * 64, j0 = blockIdx.x * 64;
    int tid = threadIdx.x;
    int wave = tid >> 6, lane = tid & 63;
    __shared__ unsigned short Bs[64][BLDS];
    __shared__ float negs[64], negsB[64];
    if (tid < 64) { negs[tid] = 0.0f; negsB[tid] = 0.0f; }

    // B tile -> registers (8 x dwordx4, coalesced)
    short8 breg[8];
#pragma unroll
    for (int m = 0; m < 8; ++m) {
        int e = m * 256 + tid;                 // 0..2047
        int row = e >> 5, ch = (e & 31) * 8;
        breg[m] = *(const short8*)(B + (size_t)(j0 + row) * CH + ch);
    }
    // A fragments direct to VGPR: lane owns row wave*16+(lane&15), chunks k*4+(lane>>4)
    const unsigned short* pa = A + (size_t)(i0 + wave * 16 + (lane & 15)) * CH + (lane >> 4) * 8;
    short8 af[8];
#pragma unroll
    for (int k = 0; k < 8; ++k) af[k] = *(const short8*)(pa + k * 32);
    // registers -> LDS
#pragma unroll
    for (int m = 0; m < 8; ++m) {
        int e = m * 256 + tid;
        int row = e >> 5, ch = (e & 31) * 8;
        *(short8*)&Bs[row][ch] = breg[m];
    }
    __syncthreads();

    f32x4 acc[4] = {{0,0,0,0},{0,0,0,0},{0,0,0,0},{0,0,0,0}};
#pragma unroll
    for (int k = 0; k < 8; ++k) {
#pragma unroll
        for (int b = 0; b < 4; ++b) {
            short8 bf = *(const short8*)&Bs[b * 16 + (lane & 15)][k * 32 + (lane >> 4) * 8];
            acc[b] = __builtin_amdgcn_mfma_f32_16x16x32_bf16(af[k], bf, acc[b], 0, 0, 0);
        }
    }

    // epilogue: C/D layout col=lane&15, row=(lane>>4)*4+reg (wave's rows: +wave*16)
    float* pd = posdot + (size_t)z * NR * 100;
    int col = lane & 15, quad = lane >> 4;
    float negB[4] = {0.0f, 0.0f, 0.0f, 0.0f};
    for (int r = 0; r < 4; ++r) {
        int irow = wave * 16 + quad * 4 + r;
        int i = i0 + irow;
        bool iok = (i < NR);
        int ci = (i / VIEWS) % NCLS;
        float negacc = 0.0f;
        for (int b = 0; b < 4; ++b) {
            int j = j0 + b * 16 + col;
            if (!iok || j >= NR) continue;
            int cj = (j / VIEWS) % NCLS;
            float d = acc[b][r] * 10.0f;   // 1/temp
            if (ci == cj) {
                int p = (j / (NCLS * VIEWS)) * VIEWS + (j % VIEWS);
                pd[(size_t)i * 100 + p] = d;
                if (mirror) {
                    int q = (i / (NCLS * VIEWS)) * VIEWS + (i % VIEWS);
                    pd[(size_t)j * 100 + q] = d;
                }
            } else {
                float e = __expf(d);
                negacc += e;
                if (mirror) negB[b] += e;
            }
        }
        for (int m = 8; m >= 1; m >>= 1) negacc += __shfl_xor(negacc, m);
        if (col == 0 && iok) negs[irow] = negacc;
    }
    if (mirror) {
        for (int b = 0; b < 4; ++b) {
            float v = negB[b];
            v += __shfl_xor(v, 16);
            v += __shfl_xor(v, 32);
            if (quad == 0) atomicAdd(&negsB[b * 16 + col], v);
        }
    }
    __syncthreads();
    if (tid < 64) {
        int i = i0 + tid;
        if (i < NR) atomicAdd(&negsum[z * NR + i], negs[tid]);
        if (mirror) {
            int j = j0 + tid;
            if (j < NR) atomicAdd(&negsum[z * NR + j], negsB[tid]);
        }
    }
}

// Kernel 4: per-anchor InfoNCE from stored same-class dots + neg exp sums.
__global__ void finalize_kernel(const float* __restrict__ negsum,
                                const float* __restrict__ posdot,
                                float* __restrict__ out) {
    int g = blockIdx.x * 256 + threadIdx.x;
    __shared__ float part[3];
    if (threadIdx.x < 3) part[threadIdx.x] = 0.0f;
    __syncthreads();
    if (g < 3 * NR) {
        int l = g / NR, i = g % NR;
        float NL = negsum[l * NR + i];
        int pself = (i / (NCLS * VIEWS)) * VIEWS + (i % VIEWS);
        const float* pd = posdot + ((size_t)l * NR + i) * 100;
        float s = 0.0f;
        for (int p = 0; p < 100; ++p) {
            if (p == pself) continue;
            float d = pd[p];
            s += d - logf(__expf(d) + NL);
        }
        atomicAdd(&part[l], s);
    }
    __syncthreads();
    if (threadIdx.x < 3)
        atomicAdd(&out[threadIdx.x], -part[threadIdx.x] * (1.0f / (99.0f * 1900.0f)));
}

extern "C" void kernel_launch(void* const* d_in, const int* in_sizes, int n_in,
                              void* d_out, int out_size, void* d_ws, size_t ws_size,
                              hipStream_t stream) {
    (void)in_sizes; (void)n_in; (void)out_size; (void)ws_size;
    const int*   label = (const int*)d_in[0];
    const float* cf    = (const float*)d_in[1];
    const float* of    = (const float*)d_in[2];
    float* ws = (float*)d_ws;
    int*            sel    = (int*)(ws + OFF_SEL);
    float*          negsum = ws + OFF_NEG;
    float*          posdot = ws + OFF_POS;
    unsigned short* fcf    = (unsigned short*)(ws + OFF_FCF);
    unsigned short* fof    = (unsigned short*)(ws + OFF_FOF);
    float*          out    = (float*)d_out;

    sample_kernel<<<NT, 256, 0, stream>>>(label, sel, negsum, out);
    gather_kernel<<<NRP, 256, 0, stream>>>(cf, of, sel, fcf, fof);
    dim3 g3(NRP / 64, NRP / 64, 3);
    gram_kernel<<<g3, 256, 0, stream>>>(fcf, fof, negsum, posdot);
    finalize_kernel<<<(3 * NR + 255) / 256, 256, 0, stream>>>(negsum, posdot, out);
}